// Round 6
// baseline (242.622 us; speedup 1.0000x reference)
//
#include <hip/hip_runtime.h>
#include <math.h>

#define NL 8
#define NP 512
#define NC 64
#define NF 128
#define NALL 192
#define NRAY (NL * NP)
#define HID 128

typedef _Float16 half8 __attribute__((ext_vector_type(8)));
typedef _Float16 half4v __attribute__((ext_vector_type(4)));
typedef float floatx16 __attribute__((ext_vector_type(16)));
typedef unsigned long long ull;

#define MFMA(a, b, c) __builtin_amdgcn_mfma_f32_32x32x16_f16((a), (b), (c), 0, 0, 0)
#define SCHED_FENCE() __builtin_amdgcn_sched_barrier(0)

// r20 = r19 structure, but the load pipeline is FORCED with sched_barrier(0)
// fences (r19 post-mortem: VGPR stayed 64 -> compiler re-sank all preloads,
// recreating r18's cold-load schedule; r18==r19==106us is one schedule).
//   per ks iteration: [issue B(ks+1) ds_reads] FENCE [6 MFMA on B(ks),A(ks)]
//                     [issue A(ks+2) global loads] FENCE
//   -> compiler emits counted lgkmcnt/vmcnt; B latency hides under the MFMA
//   cluster, A latency under a full iteration. Only 2 fences/iter (m141:
//   full order-pinning regresses).
//   A(0),A(1) issued BEFORE the store_tile VALU block (~200cy cover) since
//   __syncthreads drains vmcnt at the barrier.
// Validity check: VGPR_Count must rise to ~100-115 (A ring 16 + B ring 32
// + acc 32 + rdoff 8 + addr ~20). If still 64, fences were stripped.
// Numerics: identical values, identical MFMA order vs r16/r18/r19.

__device__ __forceinline__ float dcoarse_at(int i) {
    float t = (float)i * 0.015625f; // i/64, exact in fp32
    return 1e-3f * (1.0f - t) + 0.5f * t;
}

__device__ __forceinline__ floatx16 fzero16() {
    floatx16 z;
#pragma unroll
    for (int i = 0; i < 16; ++i) z[i] = 0.f;
    return z;
}
__device__ __forceinline__ half8 hzero8() {
    half8 z;
#pragma unroll
    for (int i = 0; i < 8; ++i) z[i] = (_Float16)0.f;
    return z;
}

// Wsp layout (per layer L in {0:w1, 1:w2}, plane p in {hi,lo}):
//   Wsp[(L*2+p)*16384 + f],  f = (((jb*8+ks)*2+lhi)*32 + l31)*8 + i
//   holding split(w[(ks*16+lhi*8+i)*128 + (jb*32+l31)]).
__global__ void prep_kernel(const float* __restrict__ w1, const float* __restrict__ w2,
                            _Float16* __restrict__ Wsp) {
    int f = blockIdx.x * 256 + threadIdx.x;   // [0, 16384)
    int layer = blockIdx.y;
    const float* w = layer ? w2 : w1;
    int i = f & 7, l31 = (f >> 3) & 31, lhi = (f >> 8) & 1, ks = (f >> 9) & 7, jb = f >> 12;
    int j = jb * 32 + l31;
    int k = ks * 16 + lhi * 8 + i;
    float v = w[k * 128 + j];
    _Float16 hi = (_Float16)v;
    Wsp[(layer * 2 + 0) * 16384 + f] = hi;
    Wsp[(layer * 2 + 1) * 16384 + f] = (_Float16)(v - (float)hi);
}

// Fused 4-layer MLP over 128 points per block, 8 waves, split-fp16 MFMA.
// MODE 0: coarse points (ray = pt>>6). MODE 1: fine points only (ray = pt>>7).
template<int MODE, int FASTW>
__global__ __launch_bounds__(512, 4) void mlp_kernel(
    const float* __restrict__ pts, const float* __restrict__ lights,
    const float* __restrict__ d_fine,
    const float* __restrict__ w0, const float* __restrict__ b0,
    const float* __restrict__ w1, const float* __restrict__ b1,
    const float* __restrict__ w2, const float* __restrict__ b2,
    const float* __restrict__ w3, const float* __restrict__ b3,
    const _Float16* __restrict__ Wsp,
    float* __restrict__ sdf_out)
{
    // H: hi plane at +0, lo plane at +32768 bytes (one address reg, imms)
    __shared__ __align__(16) _Float16 H[2 * 128 * 128];
    __shared__ _Float16 Xs[6 * 128];   // hi c0,c1,c2 then lo c0,c1,c2
    __shared__ float P2[4 * 128];      // [jq][m]

    const int tid = threadIdx.x;
    const int lane = tid & 63;
    const int wv = tid >> 6;                 // 0..7
    const int jq = wv & 3, mh = wv >> 2;     // j quarter (32 cols), m half (64 rows)
    const int l31 = lane & 31, lhi = lane >> 5;
    const int base = blockIdx.x * 128;

    // ---- phase A: per-point coords, split to fp16 hi/lo in LDS
    if (tid < 128) {
        int pt = base + tid;
        int ray; float d;
        if (MODE == 0) { ray = pt >> 6; d = dcoarse_at(pt & 63); }
        else           { ray = pt >> 7; d = d_fine[pt]; }
        int l = ray >> 9, p = ray & (NP - 1);
        float px = pts[p * 3 + 0], py = pts[p * 3 + 1], pz = pts[p * 3 + 2];
        float dx = lights[l * 3 + 0] - px, dy = lights[l * 3 + 1] - py, dz = lights[l * 3 + 2] - pz;
        float n = sqrtf(dx * dx + dy * dy + dz * dz);
        dx /= n; dy /= n; dz /= n;
        float xc[3] = { px + d * dx, py + d * dy, pz + d * dz };
#pragma unroll
        for (int c = 0; c < 3; ++c) {
            _Float16 h = (_Float16)xc[c];
            Xs[c * 128 + tid] = h;
            Xs[(3 + c) * 128 + tid] = (_Float16)(xc[c] - (float)h);
        }
    }

    const int m0 = mh * 64;              // this wave's 64-pt half
    const int mrow0 = m0 + l31;          // mt=0 LDS row (mt=1 = +32 rows = +8192 B)
    char* Hb = (char*)H;

    // Hoisted swizzled LDS read byte-offsets for mt=0 (mt=1 via +8192 imm;
    // valid because (mrow0+32)&15 == mrow0&15). Identical for both gemms.
    int rdoff[8];
#pragma unroll
    for (int ks = 0; ks < 8; ++ks) {
        int k0 = ks * 16 + lhi * 8;
        rdoff[ks] = (mrow0 * 128 + ((((k0 >> 3) ^ (mrow0 & 15)) << 3) | (k0 & 7))) * 2;
    }

    auto store_tile = [&](const floatx16& a, int mt, const float* __restrict__ bias) {
        int mrow = mrow0 + mt * 32;
#pragma unroll
        for (int g = 0; g < 4; ++g) {
            int jg = jq * 32 + 8 * g + 4 * lhi;
            half4v hq, lq;
#pragma unroll
            for (int q = 0; q < 4; ++q) {
                float v = fmaxf(a[g * 4 + q] + bias[jg + q], 0.f);
                _Float16 hi = (_Float16)v;
                hq[q] = hi;
                lq[q] = (_Float16)(v - (float)hi);
            }
            int ad = (mrow * 128 + ((((jg >> 3) ^ (mrow & 15)) << 3) | (jg & 7))) * 2;
            *(half4v*)(Hb + ad) = hq;
            *(half4v*)(Hb + ad + 32768) = lq;
        }
    };

    floatx16 acc[2];   // [mt] — 32j x 64m per wave

    // A base pointers per (L, plane), biased +2048 halves so all ks offsets
    // (ks*1024 - 4096 bytes) fit the signed-13-bit global imm field.
    const int aoff = jq * 4096 + lhi * 256 + l31 * 8 + 2048;
    const _Float16* pA0h = Wsp + 0 * 16384 + aoff;
    const _Float16* pA0l = Wsp + 1 * 16384 + aoff;
    const _Float16* pA1h = Wsp + 2 * 16384 + aoff;
    const _Float16* pA1l = Wsp + 3 * 16384 + aoff;

    // Slow-path A fetch (fp32 weights, split on the fly) — correctness fallback.
    auto ldA_slow = [&](int L, int ks, half8& ah, half8& al) {
        const float* w = L ? w2 : w1;
        int j = jq * 32 + l31, k0 = ks * 16 + lhi * 8;
#pragma unroll
        for (int i = 0; i < 8; ++i) {
            float v = w[(k0 + i) * 128 + j];
            _Float16 hi = (_Float16)v;
            ah[i] = hi;
            al[i] = (_Float16)(v - (float)hi);
        }
    };

    // ---- forced-pipeline state (FASTW path) ----
    half8 A0h, A0l, A1h, A1l;    // A ring-2: stage ks&1, refilled post-MFMA at dist 2

    auto ldB = [&](int ks, half8& b0, half8& b1, half8& b2, half8& b3) {
        char* ba = Hb + rdoff[ks];
        b0 = *(const half8*)(ba);
        b1 = *(const half8*)(ba + 8192);
        b2 = *(const half8*)(ba + 32768);
        b3 = *(const half8*)(ba + 40960);
    };

    auto preA = [&](const _Float16* ph, const _Float16* pl) {
        A0h = *(const half8*)(ph - 2048);
        A0l = *(const half8*)(pl - 2048);
        A1h = *(const half8*)(ph + 512 - 2048);
        A1l = *(const half8*)(pl + 512 - 2048);
    };

    // Pipelined gemm (FASTW): B ring-2 (issue ks+1 before MFMA ks),
    // A ring-2 (issue ks+2 after MFMA ks). Two fences/iter pin the schedule.
    auto gemm_fast = [&](const _Float16* ph, const _Float16* pl) {
        acc[0] = fzero16(); acc[1] = fzero16();
        half8 B0h0, B0h1, B0l0, B0l1, B1h0, B1h1, B1l0, B1l1;
        ldB(0, B0h0, B0h1, B0l0, B0l1);
#pragma unroll
        for (int ks = 0; ks < 8; ++ks) {
            const bool even = (ks & 1) == 0;
            if (ks < 7) {
                if (even) ldB(ks + 1, B1h0, B1h1, B1l0, B1l1);
                else      ldB(ks + 1, B0h0, B0h1, B0l0, B0l1);
            }
            SCHED_FENCE();
            {
                half8 ah  = even ? A0h  : A1h;
                half8 al  = even ? A0l  : A1l;
                half8 bh0 = even ? B0h0 : B1h0;
                half8 bh1 = even ? B0h1 : B1h1;
                half8 bl0 = even ? B0l0 : B1l0;
                half8 bl1 = even ? B0l1 : B1l1;
                acc[0] = MFMA(al, bh0, acc[0]); acc[1] = MFMA(al, bh1, acc[1]);
                acc[0] = MFMA(ah, bl0, acc[0]); acc[1] = MFMA(ah, bl1, acc[1]);
                acc[0] = MFMA(ah, bh0, acc[0]); acc[1] = MFMA(ah, bh1, acc[1]);
            }
            if (ks < 6) {
                const _Float16* hh = ph + (ks + 2) * 512 - 2048;
                const _Float16* ll = pl + (ks + 2) * 512 - 2048;
                if (even) { A0h = *(const half8*)hh; A0l = *(const half8*)ll; }
                else      { A1h = *(const half8*)hh; A1l = *(const half8*)ll; }
            }
            SCHED_FENCE();
        }
    };

    // Unpipelined fallback gemm (FASTW=0).
    auto gemm_slow = [&](int L) {
        acc[0] = fzero16(); acc[1] = fzero16();
#pragma unroll
        for (int ks = 0; ks < 8; ++ks) {
            half8 ah, al;
            ldA_slow(L, ks, ah, al);
            half8 bh0, bh1, bl0, bl1;
            ldB(ks, bh0, bh1, bl0, bl1);
            acc[0] = MFMA(al, bh0, acc[0]); acc[1] = MFMA(al, bh1, acc[1]);
            acc[0] = MFMA(ah, bl0, acc[0]); acc[1] = MFMA(ah, bl1, acc[1]);
            acc[0] = MFMA(ah, bh0, acc[0]); acc[1] = MFMA(ah, bh1, acc[1]);
        }
    };

    __syncthreads();   // Xs visible

    // ---- Layer 1: 3->128 as one K=16 MFMA step (k>=3 zero-padded)
    {
        half8 a1h = hzero8(), a1l = hzero8(), bh1[2], bl1[2];
        bh1[0] = hzero8(); bh1[1] = hzero8(); bl1[0] = hzero8(); bl1[1] = hzero8();
        if (lhi == 0) {
            int j = jq * 32 + l31;
#pragma unroll
            for (int c = 0; c < 3; ++c) {
                float v = w0[c * 128 + j];
                _Float16 hi = (_Float16)v;
                a1h[c] = hi;
                a1l[c] = (_Float16)(v - (float)hi);
            }
#pragma unroll
            for (int mt = 0; mt < 2; ++mt) {
                int m = m0 + mt * 32 + l31;
#pragma unroll
                for (int c = 0; c < 3; ++c) {
                    bh1[mt][c] = Xs[c * 128 + m];
                    bl1[mt][c] = Xs[(3 + c) * 128 + m];
                }
            }
        }
        acc[0] = fzero16(); acc[1] = fzero16();
        acc[0] = MFMA(a1l, bh1[0], acc[0]); acc[1] = MFMA(a1l, bh1[1], acc[1]);
        acc[0] = MFMA(a1h, bl1[0], acc[0]); acc[1] = MFMA(a1h, bl1[1], acc[1]);
        acc[0] = MFMA(a1h, bh1[0], acc[0]); acc[1] = MFMA(a1h, bh1[1], acc[1]);
        // gemm0 A(0),A(1): issue BEFORE the store_tile VALU block so ~200cy
        // of split/ReLU work covers the L2 latency (barrier drains vmcnt).
        if (FASTW) { preA(pA0h, pA0l); SCHED_FENCE(); }
        store_tile(acc[0], 0, b0);
        store_tile(acc[1], 1, b0);
    }
    __syncthreads();   // H1 visible

    // ---- Layer 2: H1 -> H2 (in place, barriered)
    if (FASTW) gemm_fast(pA0h, pA0l); else gemm_slow(0);
    if (FASTW) { preA(pA1h, pA1l); SCHED_FENCE(); }   // gemm1 A(0),A(1)
    __syncthreads();   // all waves done reading H1
    store_tile(acc[0], 0, b1);
    store_tile(acc[1], 1, b1);
    __syncthreads();   // H2 visible

    // ---- Layer 3 (+ Layer 4 reduce, no write-back)
    if (FASTW) gemm_fast(pA1h, pA1l); else gemm_slow(1);
#pragma unroll
    for (int mt = 0; mt < 2; ++mt) {
        float p = 0.f;
#pragma unroll
        for (int g = 0; g < 4; ++g) {
            int jg = jq * 32 + 8 * g + 4 * lhi;
#pragma unroll
            for (int q = 0; q < 4; ++q) {
                float v = fmaxf(acc[mt][g * 4 + q] + b2[jg + q], 0.f);
                p = fmaf(v, w3[jg + q], p);
            }
        }
        p += __shfl_xor(p, 32);
        if (lane < 32) P2[jq * 128 + m0 + mt * 32 + l31] = p;
    }
    __syncthreads();
    if (tid < 128)
        sdf_out[base + tid] = b3[0] + P2[tid] + P2[128 + tid] + P2[256 + tid] + P2[384 + tid];
}

// One wave per ray: shfl scans for cdf, shfl binary-search for sample_pdf
// (exact searchsorted-count semantics on strictly-increasing cdf), then a
// 256-item bitonic KEY-VALUE sort (key = float-bits(d)<<32 | idx). Outputs
// raw fine d's (for the MLP) and the sorted provenance permutation.
__global__ __launch_bounds__(256) void sample_kernel(
    const float* __restrict__ sdf_c, const float* __restrict__ u,
    float* __restrict__ d_fine, unsigned char* __restrict__ perm8) {
    const int lane = threadIdx.x & 63, wv = threadIdx.x >> 6;
    const int ray = blockIdx.x * 4 + wv;

    float sv = sdf_c[ray * NC + lane];
    float c = 1.0f / (1.0f + expf(-100.0f * sv));
    float cn = __shfl_down(c, 1);
    bool valid = lane < 63;
    float a = valid ? fmaxf((c - cn) / (c + 1e-10f), 0.f) : 0.f;
    float sh = valid ? (1.f - a + 1e-10f) : 1.f;
    float ps = sh;
#pragma unroll
    for (int off = 1; off < 64; off <<= 1) { float o = __shfl_up(ps, off); if (lane >= off) ps *= o; }
    float T = __shfl_up(ps, 1);
    if (lane == 0) T = 1.f;
    float w = valid ? (a * T + 1e-5f) : 0.f;
    float wsum = w;
#pragma unroll
    for (int off = 1; off < 64; off <<= 1) wsum += __shfl_xor(wsum, off);
    float pdf = w / wsum;
    float cs = pdf;
#pragma unroll
    for (int off = 1; off < 64; off <<= 1) { float o = __shfl_up(cs, off); if (lane >= off) cs += o; }
    float cdfv = __shfl_up(cs, 1);
    if (lane == 0) cdfv = 0.f;    // cdf[lane], strictly increasing, cdf[0]=0

    float df[2];
#pragma unroll
    for (int t = 0; t < 2; ++t) {
        float uu = u[ray * NF + t * 64 + lane];
        int lo = 0;
#pragma unroll
        for (int b = 32; b >= 1; b >>= 1) {
            float cm = __shfl(cdfv, lo + b);
            if (uu >= cm) lo += b;
        }
        int above = min(lo + 1, NC - 1);
        float cb = __shfl(cdfv, lo), ca = __shfl(cdfv, above);
        float bb = dcoarse_at(lo), ba = dcoarse_at(above);
        float denom = ca - cb;
        if (denom < 1e-5f) denom = 1.f;
        float tt = (uu - cb) / denom;
        df[t] = bb + tt * (ba - bb);
        d_fine[ray * 128 + t * 64 + lane] = df[t];
    }

    ull v[4];
    v[0] = ((ull)__float_as_uint(dcoarse_at(lane)) << 32) | (unsigned)lane;
    v[1] = ((ull)__float_as_uint(df[0]) << 32) | (unsigned)(64 + lane);
    v[2] = ((ull)__float_as_uint(df[1]) << 32) | (unsigned)(128 + lane);
    v[3] = ((ull)0x7F800000u << 32) | 255u;   // +inf pad
    for (int k = 2; k <= 256; k <<= 1) {
        for (int j = k >> 1; j > 0; j >>= 1) {
            if (j >= 64) {
                int tj = j >> 6;
#pragma unroll
                for (int t = 0; t < 4; ++t) {
                    if ((t & tj) == 0) {
                        int t2 = t ^ tj;
                        bool asc = (((t * 64) & k) == 0);
                        ull x = v[t], y = v[t2];
                        bool sw = asc ? (x > y) : (x < y);
                        if (sw) { v[t] = y; v[t2] = x; }
                    }
                }
            } else {
#pragma unroll
                for (int t = 0; t < 4; ++t) {
                    int i = t * 64 + lane;
                    ull other = __shfl_xor(v[t], j);
                    bool lower = (lane & j) == 0;
                    bool asc = ((i & k) == 0);
                    bool takeMin = (lower == asc);
                    ull mn = v[t] < other ? v[t] : other;
                    ull mx = v[t] < other ? other : v[t];
                    v[t] = takeMin ? mn : mx;
                }
            }
        }
    }
#pragma unroll
    for (int t = 0; t < 3; ++t)
        perm8[ray * NALL + t * 64 + lane] = (unsigned char)(v[t] & 0xFFu);
}

// One wave per ray: gather sdf via permutation (idx<64 -> coarse, else fine),
// then chunked (3/lane) product scan for T, occu sum, out = 1-occu.
__global__ __launch_bounds__(256) void finish_kernel(
    const float* __restrict__ sdf_c, const float* __restrict__ sdf_f,
    const unsigned char* __restrict__ perm8, float* __restrict__ out) {
    int lane = threadIdx.x & 63, wv = threadIdx.x >> 6;
    int ray = blockIdx.x * 4 + wv;
    const unsigned char* P = perm8 + (size_t)ray * NALL;
    float c[4];
#pragma unroll
    for (int t = 0; t < 4; ++t) {
        int i = lane * 3 + t;
        if (i < NALL) {
            int idx = P[i];
            float s = (idx < 64) ? sdf_c[ray * NC + idx] : sdf_f[ray * 128 + (idx - 64)];
            c[t] = 1.0f / (1.0f + expf(-100.0f * s));
        } else c[t] = 0.f;
    }
    float a[3], s[3];
#pragma unroll
    for (int t = 0; t < 3; ++t) {
        int i = lane * 3 + t;
        if (i < NALL - 1) {
            a[t] = fmaxf((c[t] - c[t + 1]) / (c[t] + 1e-10f), 0.f);
            s[t] = 1.f - a[t] + 1e-10f;
        } else { a[t] = 0.f; s[t] = 1.f; }
    }
    float chunk = s[0] * s[1] * s[2];
    float ps = chunk;
#pragma unroll
    for (int off = 1; off < 64; off <<= 1) {
        float o = __shfl_up(ps, off);
        if (lane >= off) ps *= o;
    }
    float T = __shfl_up(ps, 1);
    if (lane == 0) T = 1.f;
    float occ = a[0] * T;
    T *= s[0]; occ = fmaf(a[1], T, occ);
    T *= s[1]; occ = fmaf(a[2], T, occ);
#pragma unroll
    for (int off = 1; off < 64; off <<= 1) occ += __shfl_xor(occ, off);
    if (lane == 0) out[ray] = 1.f - occ;
}

extern "C" void kernel_launch(void* const* d_in, const int* in_sizes, int n_in,
                              void* d_out, int out_size, void* d_ws, size_t ws_size,
                              hipStream_t stream) {
    const float* pts = (const float*)d_in[0];
    const float* lights = (const float*)d_in[1];
    const float* u = (const float*)d_in[2];
    const float* w0 = (const float*)d_in[3];
    const float* b0 = (const float*)d_in[4];
    const float* w1 = (const float*)d_in[5];
    const float* b1 = (const float*)d_in[6];
    const float* w2 = (const float*)d_in[7];
    const float* b2 = (const float*)d_in[8];
    const float* w3 = (const float*)d_in[9];
    const float* b3 = (const float*)d_in[10];
    float* out = (float*)d_out;

    // ws layout:
    //   sdf_c  : NRAY*64  f32   coarse sdf — persists to finish
    //   sdf_f  : NRAY*128 f32   fine sdf
    //   d_fine : NRAY*128 f32   raw fine sample depths
    //   perm8  : NRAY*192 u8    sorted provenance permutation
    //   Wsp    : 4*16384  f16   split weights
    char* wsb = (char*)d_ws;
    float* sdf_c = (float*)wsb;
    float* sdf_f = (float*)(wsb + (size_t)NRAY * NC * 4);
    float* d_fine = (float*)(wsb + (size_t)NRAY * (NC + 128) * 4);
    unsigned char* perm8 = (unsigned char*)(wsb + (size_t)NRAY * (NC + 256) * 4);
    _Float16* Wsp = (_Float16*)(wsb + (size_t)NRAY * (NC + 256) * 4 + (size_t)NRAY * NALL);
    const size_t need = (size_t)NRAY * (NC + 256) * 4 + (size_t)NRAY * NALL
                      + (size_t)4 * 16384 * sizeof(_Float16);
    const bool fast = ws_size >= need;

    if (fast) {
        prep_kernel<<<dim3(64, 2), 256, 0, stream>>>(w1, w2, Wsp);
        mlp_kernel<0, 1><<<(NRAY * NC) / 128, 512, 0, stream>>>(
            pts, lights, nullptr, w0, b0, w1, b1, w2, b2, w3, b3, Wsp, sdf_c);
        sample_kernel<<<NRAY / 4, 256, 0, stream>>>(sdf_c, u, d_fine, perm8);
        mlp_kernel<1, 1><<<(NRAY * 128) / 128, 512, 0, stream>>>(
            pts, lights, d_fine, w0, b0, w1, b1, w2, b2, w3, b3, Wsp, sdf_f);
    } else {
        mlp_kernel<0, 0><<<(NRAY * NC) / 128, 512, 0, stream>>>(
            pts, lights, nullptr, w0, b0, w1, b1, w2, b2, w3, b3, nullptr, sdf_c);
        sample_kernel<<<NRAY / 4, 256, 0, stream>>>(sdf_c, u, d_fine, perm8);
        mlp_kernel<1, 0><<<(NRAY * 128) / 128, 512, 0, stream>>>(
            pts, lights, d_fine, w0, b0, w1, b1, w2, b2, w3, b3, nullptr, sdf_f);
    }
    finish_kernel<<<NRAY / 4, 256, 0, stream>>>(sdf_c, sdf_f, perm8, out);
}